// Round 5
// baseline (555.160 us; speedup 1.0000x reference)
//
#include <hip/hip_runtime.h>
#include <hip/hip_cooperative_groups.h>
#include <math.h>

namespace cg = cooperative_groups;

#define CHANNEL 128
#define NEG_INF (-1e30f)
#define MAXBLOCKS 2048

__global__ void __launch_bounds__(256, 4) fused_kernel(
    const float* __restrict__ ent, const float* __restrict__ relw,
    const float* __restrict__ W, const int* __restrict__ eidx,
    const int* __restrict__ etype, float* __restrict__ out,
    int* __restrict__ deg, int* __restrict__ rowptr, int* __restrict__ cursor,
    int* __restrict__ partial, int2* __restrict__ recs, float2* __restrict__ sc,
    float* __restrict__ kr, float* __restrict__ P2, float* __restrict__ rel_norm,
    int N, int E, int R)
{
    cg::grid_group grid = cg::this_grid();
    const int t = threadIdx.x;
    const int tid = blockIdx.x * 256 + t;
    const int nth = gridDim.x * 256;
    __shared__ int sh[256];

    // ---- P0: zero deg; kr[j][c] = sum_k relw[j][k]*W[k][c]; rel_norm ----
    for (int i = tid; i < N; i += nth) deg[i] = 0;
    for (int i = tid; i < R * CHANNEL; i += nth) {
        int j = i >> 7, c = i & 127;
        const float* rw = relw + j * CHANNEL;
        float acc = 0.f;
        for (int k = 0; k < CHANNEL; ++k) acc += rw[k] * W[k * CHANNEL + c];
        kr[i] = acc;
    }
    for (int i = tid; i < R; i += nth) {
        const float* rw = relw + i * CHANNEL;
        float s = 0.f;
        for (int k = 0; k < CHANNEL; ++k) s += rw[k] * rw[k];
        rel_norm[i] = s;
    }
    grid.sync();

    // ---- P1: P2[j][k] = (1/16) sum_c W[k][c]*kr[j][c]; count degrees ----
    for (int i = tid; i < R * CHANNEL; i += nth) {
        int j = i >> 7, k = i & 127;
        const float* wrow = W + k * CHANNEL;
        const float* krow = kr + j * CHANNEL;
        float acc = 0.f;
        for (int c = 0; c < CHANNEL; ++c) acc += wrow[c] * krow[c];
        P2[i] = acc * 0.0625f;
    }
    for (int e = tid; e < E; e += nth) atomicAdd(deg + eidx[e], 1);
    grid.sync();

    // ---- P2: per-block local exclusive scan of a contiguous chunk ----
    const int chunk = (N + gridDim.x - 1) / gridDim.x;   // <= 256 given grid >= 256
    const int base = blockIdx.x * chunk;
    {
        int i = base + t;
        int v = (t < chunk && i < N) ? deg[i] : 0;
        sh[t] = v;
        __syncthreads();
        for (int off = 1; off < 256; off <<= 1) {
            int u = (t >= off) ? sh[t - off] : 0;
            __syncthreads();
            sh[t] += u;
            __syncthreads();
        }
        if (t < chunk && i < N) rowptr[i] = sh[t] - v;   // local exclusive
        if (t == 255) partial[blockIdx.x] = sh[255];
        __syncthreads();
    }
    grid.sync();

    // ---- P3: add prefix of block partials; init cursor; rowptr[N] ----
    {
        int psum = 0;
        for (int i = t; i < blockIdx.x; i += 256) psum += partial[i];
        sh[t] = psum;
        __syncthreads();
        for (int off = 128; off; off >>= 1) {
            if (t < off) sh[t] += sh[t + off];
            __syncthreads();
        }
        int prefix = sh[0];
        int i = base + t;
        if (t < chunk && i < N) {
            int v = rowptr[i] + prefix;
            rowptr[i] = v;
            cursor[i] = v;
        }
        if (tid == 0) rowptr[N] = E;
    }
    grid.sync();

    // ---- P4: scatter edges into CSR bins: recs = { tail | type<<20, edge_id } ----
    for (int e = tid; e < E; e += nth) {
        int h = eidx[e];
        int tl = eidx[E + e];
        int r = etype[e] - 1;
        int pos = atomicAdd(cursor + h, 1);
        recs[pos] = make_int2(tl | (r << 20), e);
    }
    grid.sync();

    // ---- P5: one wave per head; fused dots + double softmax in registers ----
    const int wid0 = tid >> 6;
    const int nw = nth >> 6;
    const int lane = t & 63;
    const int group = lane >> 4;
    const int sub = lane & 15;

    for (int h = wid0; h < N; h += nw) {
        int start = rowptr[h];
        int deg_h = rowptr[h + 1] - start;
        if (deg_h == 0) continue;
        const float4* hp = (const float4*)(ent + (size_t)h * CHANNEL);
        float4 h0 = hp[sub], h1 = hp[sub + 16];

        if (deg_h <= 64) {
            // fast path: dot sweep (16 lanes/edge), transpose to lane-per-edge regs
            float d1c = 0.f, d2c = NEG_INF;
            int eidc = 0, typc = 0;
            int iters = (deg_h + 3) >> 2;
            for (int i = 0; i < iters; ++i) {
                int idx = i * 4 + group;
                bool act = idx < deg_h;
                int j = start + (act ? idx : 0);
                int2 rc = recs[j];
                int tail = rc.x & 0xFFFFF;
                int typ = rc.x >> 20;
                float d1 = 0.f, d2 = 0.f;
                if (act) {
                    const float4* tp = (const float4*)(ent + (size_t)tail * CHANNEL);
                    const float4* rp = (const float4*)(P2 + typ * CHANNEL);
                    float4 t0 = tp[sub], t1 = tp[sub + 16];
                    float4 r0 = rp[sub], r1 = rp[sub + 16];
                    d1 = h0.x * t0.x + h0.y * t0.y + h0.z * t0.z + h0.w * t0.w
                       + h1.x * t1.x + h1.y * t1.y + h1.z * t1.z + h1.w * t1.w;
                    d2 = h0.x * r0.x + h0.y * r0.y + h0.z * r0.z + h0.w * r0.w
                       + h1.x * r1.x + h1.y * r1.y + h1.z * r1.z + h1.w * r1.w;
                }
#pragma unroll
                for (int m = 1; m <= 8; m <<= 1) {
                    d1 += __shfl_xor(d1, m);
                    d2 += __shfl_xor(d2, m);
                }
                // lane l holds edge l = 4*(l>>2) + (l&3), sourced from group (l&3)
                int srcl = (lane & 3) * 16;
                float td1 = __shfl(d1, srcl);
                float td2 = __shfl(d2, srcl);
                int teid = __shfl(rc.y, srcl);
                int ttyp = __shfl(typ, srcl);
                if ((lane >> 2) == i) {
                    d1c = td1; d2c = td2; eidc = teid; typc = ttyp;
                }
            }
            bool valid = lane < deg_h;
            // softmax 1 over d2
            float m1 = valid ? d2c : NEG_INF;
#pragma unroll
            for (int m = 32; m; m >>= 1) m1 = fmaxf(m1, __shfl_xor(m1, m));
            float e1 = valid ? expf(d2c - m1) : 0.f;
            float s1 = e1;
#pragma unroll
            for (int m = 32; m; m >>= 1) s1 += __shfl_xor(s1, m);
            float rs = e1 / s1;
            // trip score + softmax 2
            float stv = d1c + rs * rs * rel_norm[typc];
            float m2 = valid ? stv : NEG_INF;
#pragma unroll
            for (int m = 32; m; m >>= 1) m2 = fmaxf(m2, __shfl_xor(m2, m));
            float e2 = valid ? expf(stv - m2) : 0.f;
            float s2 = e2;
#pragma unroll
            for (int m = 32; m; m >>= 1) s2 += __shfl_xor(s2, m);
            if (valid) out[eidc] = e2 / s2;
        } else {
            // slow path (deg > 64): multi-sweep via sc scratch
            float pm1 = NEG_INF;
            for (int k0 = 0; k0 < deg_h; k0 += 4) {
                int idx = k0 + group;
                bool act = idx < deg_h;
                int j = start + (act ? idx : 0);
                int2 rc = recs[j];
                float d1 = 0.f, d2 = 0.f;
                if (act) {
                    int tail = rc.x & 0xFFFFF;
                    int typ = rc.x >> 20;
                    const float4* tp = (const float4*)(ent + (size_t)tail * CHANNEL);
                    const float4* rp = (const float4*)(P2 + typ * CHANNEL);
                    float4 t0 = tp[sub], t1 = tp[sub + 16];
                    float4 r0 = rp[sub], r1 = rp[sub + 16];
                    d1 = h0.x * t0.x + h0.y * t0.y + h0.z * t0.z + h0.w * t0.w
                       + h1.x * t1.x + h1.y * t1.y + h1.z * t1.z + h1.w * t1.w;
                    d2 = h0.x * r0.x + h0.y * r0.y + h0.z * r0.z + h0.w * r0.w
                       + h1.x * r1.x + h1.y * r1.y + h1.z * r1.z + h1.w * r1.w;
                }
#pragma unroll
                for (int m = 1; m <= 8; m <<= 1) {
                    d1 += __shfl_xor(d1, m);
                    d2 += __shfl_xor(d2, m);
                }
                if (act) {
                    if (sub == 0) sc[j] = make_float2(d1, d2);
                    pm1 = fmaxf(pm1, d2);
                }
            }
            pm1 = fmaxf(pm1, __shfl_xor(pm1, 16));
            pm1 = fmaxf(pm1, __shfl_xor(pm1, 32));
            float m1 = pm1;

            float s1 = 0.f;
            for (int k = lane; k < deg_h; k += 64) s1 += expf(sc[start + k].y - m1);
#pragma unroll
            for (int m = 32; m; m >>= 1) s1 += __shfl_xor(s1, m);

            float pm2 = NEG_INF;
            for (int k = lane; k < deg_h; k += 64) {
                float2 v = sc[start + k];
                int typ = recs[start + k].x >> 20;
                float e1 = expf(v.y - m1);
                float rsv = e1 / s1;
                float stv = v.x + rsv * rsv * rel_norm[typ];
                sc[start + k].x = stv;
                pm2 = fmaxf(pm2, stv);
            }
#pragma unroll
            for (int m = 32; m; m >>= 1) pm2 = fmaxf(pm2, __shfl_xor(pm2, m));
            float m2 = pm2;

            float s2 = 0.f;
            for (int k = lane; k < deg_h; k += 64) {
                float e2 = expf(sc[start + k].x - m2);
                sc[start + k].y = e2;
                s2 += e2;
            }
#pragma unroll
            for (int m = 32; m; m >>= 1) s2 += __shfl_xor(s2, m);
            float inv = 1.f / s2;

            for (int k = lane; k < deg_h; k += 64)
                out[recs[start + k].y] = sc[start + k].y * inv;
        }
    }
}

extern "C" void kernel_launch(void* const* d_in, const int* in_sizes, int n_in,
                              void* d_out, int out_size, void* d_ws, size_t ws_size,
                              hipStream_t stream) {
    const float* ent   = (const float*)d_in[0];
    const float* relw  = (const float*)d_in[2];
    const float* W     = (const float*)d_in[3];
    const int*   eidx  = (const int*)d_in[4];
    const int*   etype = (const int*)d_in[5];
    float* out = (float*)d_out;

    int E = in_sizes[5];
    int N = in_sizes[0] / CHANNEL;
    int R = in_sizes[2] / CHANNEL;

    char* basep = (char*)d_ws;
    auto alloc = [&](size_t bytes) {
        char* p = basep;
        basep += (bytes + 15) & ~(size_t)15;
        return p;
    };
    int*    deg      = (int*)alloc((size_t)N * 4);
    int*    rowptr   = (int*)alloc((size_t)(N + 1) * 4);
    int*    cursor   = (int*)alloc((size_t)N * 4);
    int*    partial  = (int*)alloc((size_t)MAXBLOCKS * 4);
    int2*   recs     = (int2*)alloc((size_t)E * 8);
    float2* sc       = (float2*)alloc((size_t)E * 8);
    float*  kr       = (float*)alloc((size_t)R * CHANNEL * 4);
    float*  P2       = (float*)alloc((size_t)R * CHANNEL * 4);
    float*  rel_norm = (float*)alloc((size_t)R * 4);

    // Size the grid from the runtime's own occupancy accounting so the
    // cooperative-launch residency check cannot reject it. Host-side
    // queries only — graph-capture-safe and deterministic.
    int blocksPerCU = 0;
    if (hipOccupancyMaxActiveBlocksPerMultiprocessor(
            &blocksPerCU, (const void*)fused_kernel, 256, 0) != hipSuccess ||
        blocksPerCU < 1) {
        blocksPerCU = 1;
    }
    int dev = 0;
    hipGetDevice(&dev);
    int numCU = 0;
    if (hipDeviceGetAttribute(&numCU, hipDeviceAttributeMultiprocessorCount, dev) != hipSuccess ||
        numCU < 1) {
        numCU = 256;
    }
    long long g = (long long)blocksPerCU * numCU;
    if (g > MAXBLOCKS) g = MAXBLOCKS;
    if (g < 256) g = 256;   // keeps chunk = ceil(N/grid) <= 256 for the scan
    int nblocks = (int)g;

    void* args[] = {
        (void*)&ent, (void*)&relw, (void*)&W, (void*)&eidx, (void*)&etype,
        (void*)&out, (void*)&deg, (void*)&rowptr, (void*)&cursor, (void*)&partial,
        (void*)&recs, (void*)&sc, (void*)&kr, (void*)&P2, (void*)&rel_norm,
        (void*)&N, (void*)&E, (void*)&R
    };
    hipLaunchCooperativeKernel((const void*)fused_kernel, dim3(nblocks), dim3(256),
                               args, 0, stream);
}

// Round 6
// 141.979 us; speedup vs baseline: 3.9102x; 3.9102x over previous
//
#include <hip/hip_runtime.h>
#include <hip/hip_bf16.h>
#include <math.h>

#define CHANNEL 128
#define NEG_INF (-1e30f)

// --- precompute P2[r] = (W W^T relw[r]^T)/16 and rel_norm[r] = ||relw[r]||^2 ---
__global__ void prep_kernel(const float* __restrict__ relw, const float* __restrict__ W,
                            float* __restrict__ P2, float* __restrict__ rel_norm) {
    __shared__ float rw[CHANNEL];
    __shared__ float kr[CHANNEL];
    __shared__ float red[CHANNEL];
    int j = blockIdx.x;
    int c = threadIdx.x;
    float v = relw[j * CHANNEL + c];
    rw[c] = v;
    red[c] = v * v;
    __syncthreads();
    for (int s = CHANNEL / 2; s > 0; s >>= 1) {
        if (c < s) red[c] += red[c + s];
        __syncthreads();
    }
    if (c == 0) rel_norm[j] = red[0];
    float acc = 0.f;
    for (int k = 0; k < CHANNEL; ++k) acc += rw[k] * W[k * CHANNEL + c];
    kr[c] = acc;
    __syncthreads();
    float acc2 = 0.f;
    for (int cc = 0; cc < CHANNEL; ++cc) acc2 += W[c * CHANNEL + cc] * kr[cc];
    P2[j * CHANNEL + c] = acc2 * 0.0625f;
}

__global__ void deg_count_kernel(const int* __restrict__ eidx, int* __restrict__ deg, int E) {
    int e = blockIdx.x * blockDim.x + threadIdx.x;
    if (e < E) atomicAdd(deg + eidx[e], 1);
}

// hierarchical scan stage 1: per-block (256) exclusive scan, emit block totals
__global__ void scan1_kernel(const int* __restrict__ deg, int* __restrict__ rowptr,
                             int* __restrict__ partial, int N) {
    __shared__ int sh[256];
    int t = threadIdx.x;
    int i = blockIdx.x * 256 + t;
    int v = (i < N) ? deg[i] : 0;
    sh[t] = v;
    __syncthreads();
    for (int off = 1; off < 256; off <<= 1) {
        int u = (t >= off) ? sh[t - off] : 0;
        __syncthreads();
        sh[t] += u;
        __syncthreads();
    }
    if (i < N) rowptr[i] = sh[t] - v;
    if (t == 255) partial[blockIdx.x] = sh[255];
}

__global__ void scan2_kernel(int* __restrict__ partial, int nblk) {
    __shared__ int sh[1024];
    int t = threadIdx.x;
    int v = (t < nblk) ? partial[t] : 0;
    sh[t] = v;
    __syncthreads();
    for (int off = 1; off < 1024; off <<= 1) {
        int u = (t >= off) ? sh[t - off] : 0;
        __syncthreads();
        sh[t] += u;
        __syncthreads();
    }
    if (t < nblk) partial[t] = sh[t] - v;
}

__global__ void scan3_kernel(int* __restrict__ rowptr, int* __restrict__ cursor,
                             const int* __restrict__ partial, int N, int E) {
    int i = blockIdx.x * 256 + threadIdx.x;
    if (i < N) {
        int v = rowptr[i] + partial[blockIdx.x];
        rowptr[i] = v;
        cursor[i] = v;
    } else if (i == N) {
        rowptr[N] = E;
    }
}

__global__ void scatter_kernel(const int* __restrict__ eidx, const int* __restrict__ etype,
                               int* __restrict__ cursor, int2* __restrict__ recs, int E) {
    int e = blockIdx.x * blockDim.x + threadIdx.x;
    if (e >= E) return;
    int h = eidx[e];
    int t = eidx[E + e];
    int r = etype[e] - 1;
    int pos = atomicAdd(cursor + h, 1);
    recs[pos] = make_int2(t | (r << 20), e);
}

struct RowSet { float4 t0, t1, r0, r1; };

// one wave per head; coalesced recs load + depth-2 pipelined row gathers
__global__ void __launch_bounds__(256, 4) main_kernel(
        const float* __restrict__ ent, const float* __restrict__ P2,
        const float* __restrict__ rel_norm, const int* __restrict__ rowptr,
        const int2* __restrict__ recs, float2* __restrict__ sc,
        float* __restrict__ out, int N) {
    int wid = (int)((blockIdx.x * blockDim.x + threadIdx.x) >> 6);
    if (wid >= N) return;
    int lane = threadIdx.x & 63;
    int grp = lane >> 4;
    int sub = lane & 15;

    int start = rowptr[wid];
    int deg_h = rowptr[wid + 1] - start;
    if (deg_h == 0) return;

    const float4* hp = (const float4*)(ent + (size_t)wid * CHANNEL);
    float4 h0 = hp[sub], h1 = hp[sub + 16];

    if (deg_h <= 64) {
        // lane l owns edge l (clamped): one coalesced 8B load for the whole row set
        int lc = lane < deg_h ? lane : deg_h - 1;
        int2 rc = recs[start + lc];
        int iters = (deg_h + 3) >> 2;

        auto issue = [&](int g) -> RowSet {
            RowSet s;
            int e = 4 * g + grp;
            int ec = e < deg_h ? e : deg_h - 1;
            int rcx = __shfl(rc.x, ec);
            int tail = rcx & 0xFFFFF;
            int typ = rcx >> 20;
            const float4* tp = (const float4*)(ent + (size_t)tail * CHANNEL);
            const float4* rp = (const float4*)(P2 + typ * CHANNEL);
            s.t0 = tp[sub]; s.t1 = tp[sub + 16];
            s.r0 = rp[sub]; s.r1 = rp[sub + 16];
            return s;
        };

        float d1c = 0.f, d2c = 0.f;
        auto compute = [&](int g, const RowSet& s) {
            float d1 = h0.x * s.t0.x + h0.y * s.t0.y + h0.z * s.t0.z + h0.w * s.t0.w
                     + h1.x * s.t1.x + h1.y * s.t1.y + h1.z * s.t1.z + h1.w * s.t1.w;
            float d2 = h0.x * s.r0.x + h0.y * s.r0.y + h0.z * s.r0.z + h0.w * s.r0.w
                     + h1.x * s.r1.x + h1.y * s.r1.y + h1.z * s.r1.z + h1.w * s.r1.w;
#pragma unroll
            for (int m = 1; m <= 8; m <<= 1) {
                d1 += __shfl_xor(d1, m);
                d2 += __shfl_xor(d2, m);
            }
            int srcl = (lane & 3) * 16;
            float td1 = __shfl(d1, srcl);
            float td2 = __shfl(d2, srcl);
            if ((lane >> 2) == g) { d1c = td1; d2c = td2; }
        };

        RowSet A = issue(0);
        int g = 0;
        while (g < iters) {
            RowSet B = issue(g + 1);   // may be past end: clamped, harmless
            compute(g, A);
            ++g;
            if (g >= iters) break;
            A = issue(g + 1);
            compute(g, B);
            ++g;
        }

        bool valid = lane < deg_h;
        int typc = rc.x >> 20;
        int eidc = rc.y;
        // softmax 1 over d2
        float m1 = valid ? d2c : NEG_INF;
#pragma unroll
        for (int m = 32; m; m >>= 1) m1 = fmaxf(m1, __shfl_xor(m1, m));
        float e1 = valid ? expf(d2c - m1) : 0.f;
        float s1 = e1;
#pragma unroll
        for (int m = 32; m; m >>= 1) s1 += __shfl_xor(s1, m);
        float rs = e1 / s1;
        // trip score + softmax 2
        float stv = d1c + rs * rs * rel_norm[typc];
        float m2 = valid ? stv : NEG_INF;
#pragma unroll
        for (int m = 32; m; m >>= 1) m2 = fmaxf(m2, __shfl_xor(m2, m));
        float e2 = valid ? expf(stv - m2) : 0.f;
        float s2 = e2;
#pragma unroll
        for (int m = 32; m; m >>= 1) s2 += __shfl_xor(s2, m);
        if (valid) out[eidc] = e2 / s2;
    } else {
        // slow path (deg > 64): multi-sweep via sc scratch
        float pm1 = NEG_INF;
        for (int k0 = 0; k0 < deg_h; k0 += 4) {
            int idx = k0 + grp;
            bool act = idx < deg_h;
            int j = start + (act ? idx : 0);
            int2 rc = recs[j];
            float d1 = 0.f, d2 = 0.f;
            if (act) {
                int tail = rc.x & 0xFFFFF;
                int typ = rc.x >> 20;
                const float4* tp = (const float4*)(ent + (size_t)tail * CHANNEL);
                const float4* rp = (const float4*)(P2 + typ * CHANNEL);
                float4 t0 = tp[sub], t1 = tp[sub + 16];
                float4 r0 = rp[sub], r1 = rp[sub + 16];
                d1 = h0.x * t0.x + h0.y * t0.y + h0.z * t0.z + h0.w * t0.w
                   + h1.x * t1.x + h1.y * t1.y + h1.z * t1.z + h1.w * t1.w;
                d2 = h0.x * r0.x + h0.y * r0.y + h0.z * r0.z + h0.w * r0.w
                   + h1.x * r1.x + h1.y * r1.y + h1.z * r1.z + h1.w * r1.w;
            }
#pragma unroll
            for (int m = 1; m <= 8; m <<= 1) {
                d1 += __shfl_xor(d1, m);
                d2 += __shfl_xor(d2, m);
            }
            if (act) {
                if (sub == 0) sc[j] = make_float2(d1, d2);
                pm1 = fmaxf(pm1, d2);
            }
        }
        pm1 = fmaxf(pm1, __shfl_xor(pm1, 16));
        pm1 = fmaxf(pm1, __shfl_xor(pm1, 32));
        float m1 = pm1;

        float s1 = 0.f;
        for (int k = lane; k < deg_h; k += 64) s1 += expf(sc[start + k].y - m1);
#pragma unroll
        for (int m = 32; m; m >>= 1) s1 += __shfl_xor(s1, m);

        float pm2 = NEG_INF;
        for (int k = lane; k < deg_h; k += 64) {
            float2 v = sc[start + k];
            int typ = recs[start + k].x >> 20;
            float e1 = expf(v.y - m1);
            float rsv = e1 / s1;
            float stv = v.x + rsv * rsv * rel_norm[typ];
            sc[start + k].x = stv;
            pm2 = fmaxf(pm2, stv);
        }
#pragma unroll
        for (int m = 32; m; m >>= 1) pm2 = fmaxf(pm2, __shfl_xor(pm2, m));
        float m2 = pm2;

        float s2 = 0.f;
        for (int k = lane; k < deg_h; k += 64) {
            float e2 = expf(sc[start + k].x - m2);
            sc[start + k].y = e2;
            s2 += e2;
        }
#pragma unroll
        for (int m = 32; m; m >>= 1) s2 += __shfl_xor(s2, m);
        float inv = 1.f / s2;

        for (int k = lane; k < deg_h; k += 64)
            out[recs[start + k].y] = sc[start + k].y * inv;
    }
}

extern "C" void kernel_launch(void* const* d_in, const int* in_sizes, int n_in,
                              void* d_out, int out_size, void* d_ws, size_t ws_size,
                              hipStream_t stream) {
    const float* ent   = (const float*)d_in[0];
    const float* relw  = (const float*)d_in[2];
    const float* W     = (const float*)d_in[3];
    const int*   eidx  = (const int*)d_in[4];
    const int*   etype = (const int*)d_in[5];
    float* out = (float*)d_out;

    const int E = in_sizes[5];
    const int N = in_sizes[0] / CHANNEL;
    const int R = in_sizes[2] / CHANNEL;

    char* base = (char*)d_ws;
    auto alloc = [&](size_t bytes) {
        char* p = base;
        base += (bytes + 15) & ~(size_t)15;
        return p;
    };
    int*    deg      = (int*)alloc((size_t)N * 4);
    int*    rowptr   = (int*)alloc((size_t)(N + 1) * 4);
    int*    cursor   = (int*)alloc((size_t)N * 4);
    int*    partial  = (int*)alloc(1024 * 4);
    int2*   recs     = (int2*)alloc((size_t)E * 8);
    float2* sc       = (float2*)alloc((size_t)E * 8);
    float*  P2       = (float*)alloc((size_t)R * CHANNEL * 4);
    float*  rel_norm = (float*)alloc((size_t)R * 4);

    hipMemsetAsync(deg, 0, (size_t)N * 4, stream);

    prep_kernel<<<R, CHANNEL, 0, stream>>>(relw, W, P2, rel_norm);

    int be = (E + 255) / 256;
    deg_count_kernel<<<be, 256, 0, stream>>>(eidx, deg, E);

    int nblk = (N + 255) / 256;  // 157 for N=40000; must be <= 1024
    scan1_kernel<<<nblk, 256, 0, stream>>>(deg, rowptr, partial, N);
    scan2_kernel<<<1, 1024, 0, stream>>>(partial, nblk);
    scan3_kernel<<<(N + 256) / 256, 256, 0, stream>>>(rowptr, cursor, partial, N, E);

    scatter_kernel<<<be, 256, 0, stream>>>(eidx, etype, cursor, recs, E);

    int bm = (N + 3) / 4;  // 4 waves per block, one wave per head
    main_kernel<<<bm, 256, 0, stream>>>(ent, P2, rel_norm, rowptr, recs, sc, out, N);
}

// Round 7
// 107.132 us; speedup vs baseline: 5.1820x; 1.3253x over previous
//
#include <hip/hip_runtime.h>
#include <hip/hip_bf16.h>
#include <math.h>

#define CHANNEL 128
#define NEG_INF (-1e30f)

__device__ __forceinline__ float dot4(float4 a, float4 b) {
    return a.x * b.x + a.y * b.y + a.z * b.z + a.w * b.w;
}

// blocks [0,R): prep  P2[r] = (W W^T relw[r]^T)/16, rel_norm[r] = ||relw[r]||^2
// blocks [R,..): count degrees + per-edge rank (atomic return order)
__global__ void __launch_bounds__(256) prep_count_kernel(
    const float* __restrict__ relw, const float* __restrict__ W,
    const int* __restrict__ eidx, float* __restrict__ P2,
    float* __restrict__ rel_norm, int* __restrict__ deg,
    unsigned short* __restrict__ rank, int E, int R)
{
    int b = blockIdx.x;
    if (b < R) {
        __shared__ float rw[CHANNEL];
        __shared__ float kr[CHANNEL];
        __shared__ float red[CHANNEL];
        int c = threadIdx.x;
        int j = b;
        if (c < CHANNEL) {
            float v = relw[j * CHANNEL + c];
            rw[c] = v;
            red[c] = v * v;
        }
        __syncthreads();
        for (int s = CHANNEL / 2; s > 0; s >>= 1) {
            if (c < s) red[c] += red[c + s];
            __syncthreads();
        }
        if (c == 0) rel_norm[j] = red[0];
        if (c < CHANNEL) {
            float acc = 0.f;
            for (int k = 0; k < CHANNEL; ++k) acc += rw[k] * W[k * CHANNEL + c];
            kr[c] = acc;
        }
        __syncthreads();
        if (c < CHANNEL) {
            float acc2 = 0.f;
            for (int cc = 0; cc < CHANNEL; ++cc) acc2 += W[c * CHANNEL + cc] * kr[cc];
            P2[j * CHANNEL + c] = acc2 * 0.0625f;
        }
    } else {
        int e = (b - R) * 256 + threadIdx.x;
        if (e < E) rank[e] = (unsigned short)atomicAdd(deg + eidx[e], 1);
    }
}

// per-block (256) exclusive scan of deg; raw = local exclusive, partial = block totals
__global__ void scan1_kernel(const int* __restrict__ deg, int* __restrict__ raw,
                             int* __restrict__ partial, int N) {
    __shared__ int sh[256];
    int t = threadIdx.x;
    int i = blockIdx.x * 256 + t;
    int v = (i < N) ? deg[i] : 0;
    sh[t] = v;
    __syncthreads();
    for (int off = 1; off < 256; off <<= 1) {
        int u = (t >= off) ? sh[t - off] : 0;
        __syncthreads();
        sh[t] += u;
        __syncthreads();
    }
    if (i < N) raw[i] = sh[t] - v;
    if (t == 255) partial[blockIdx.x] = sh[255];
}

// single block: exclusive scan of block totals (nblk <= 1024)
__global__ void scan2_kernel(int* __restrict__ partial, int nblk) {
    __shared__ int sh[1024];
    int t = threadIdx.x;
    int v = (t < nblk) ? partial[t] : 0;
    sh[t] = v;
    __syncthreads();
    for (int off = 1; off < 1024; off <<= 1) {
        int u = (t >= off) ? sh[t - off] : 0;
        __syncthreads();
        sh[t] += u;
        __syncthreads();
    }
    if (t < nblk) partial[t] = sh[t] - v;
}

// atomic-free placement: recs[start(h) + rank[e]] = { tail | type<<20, edge_id }
__global__ void place_kernel(const int* __restrict__ eidx, const int* __restrict__ etype,
                             const int* __restrict__ raw, const int* __restrict__ partial,
                             const unsigned short* __restrict__ rank,
                             int2* __restrict__ recs, int E) {
    int e = blockIdx.x * 256 + threadIdx.x;
    if (e >= E) return;
    int h = eidx[e];
    int t = eidx[E + e];
    int r = etype[e] - 1;
    int pos = raw[h] + partial[h >> 8] + (int)rank[e];
    recs[pos] = make_int2(t | (r << 20), e);
}

struct Row8 { float4 t0, t1, t2, t3, r0, r1, r2, r3; };

// one wave per head; 8 lanes/edge (8 edges in flight), depth-2 pipelined gathers
__global__ void __launch_bounds__(256, 4) main_kernel(
        const float* __restrict__ ent, const float* __restrict__ P2,
        const float* __restrict__ rel_norm, const int* __restrict__ raw,
        const int* __restrict__ partial, const int2* __restrict__ recs,
        float2* __restrict__ sc, float* __restrict__ out, int N, int E) {
    int wid = (int)((blockIdx.x * blockDim.x + threadIdx.x) >> 6);
    if (wid >= N) return;
    int lane = threadIdx.x & 63;

    int s0 = raw[wid] + partial[wid >> 8];
    int nxt = (wid + 1 < N) ? (raw[wid + 1] + partial[(wid + 1) >> 8]) : E;
    int deg_h = nxt - s0;
    if (deg_h == 0) return;

    if (deg_h <= 64) {
        int grp = lane >> 3;   // edge slot 0..7
        int sub = lane & 7;    // row quarter 0..7
        const float4* hp = (const float4*)(ent + (size_t)wid * CHANNEL);
        float4 h0 = hp[sub], h1 = hp[sub + 8], h2 = hp[sub + 16], h3 = hp[sub + 24];

        // lane l owns edge l (clamped): one coalesced 8B load for the row set
        int lc = lane < deg_h ? lane : deg_h - 1;
        int2 rc = recs[s0 + lc];
        int iters = (deg_h + 7) >> 3;

        auto issue = [&](int g) -> Row8 {
            Row8 s;
            int e = 8 * g + grp;
            int ec = e < deg_h ? e : deg_h - 1;
            int rcx = __shfl(rc.x, ec);
            int tail = rcx & 0xFFFFF;
            int typ = rcx >> 20;
            const float4* tp = (const float4*)(ent + (size_t)tail * CHANNEL);
            const float4* rp = (const float4*)(P2 + typ * CHANNEL);
            s.t0 = tp[sub]; s.t1 = tp[sub + 8]; s.t2 = tp[sub + 16]; s.t3 = tp[sub + 24];
            s.r0 = rp[sub]; s.r1 = rp[sub + 8]; s.r2 = rp[sub + 16]; s.r3 = rp[sub + 24];
            return s;
        };

        float d1c = 0.f, d2c = 0.f;
        auto compute = [&](int g, const Row8& s) {
            float d1 = dot4(h0, s.t0) + dot4(h1, s.t1) + dot4(h2, s.t2) + dot4(h3, s.t3);
            float d2 = dot4(h0, s.r0) + dot4(h1, s.r1) + dot4(h2, s.r2) + dot4(h3, s.r3);
#pragma unroll
            for (int m = 1; m <= 4; m <<= 1) {
                d1 += __shfl_xor(d1, m);
                d2 += __shfl_xor(d2, m);
            }
            int srcl = (lane & 7) * 8;
            float td1 = __shfl(d1, srcl);
            float td2 = __shfl(d2, srcl);
            if ((lane >> 3) == g) { d1c = td1; d2c = td2; }
        };

        Row8 A = issue(0);
        int g = 0;
        while (g < iters) {
            Row8 B = issue(g + 1);   // clamped past end, harmless
            compute(g, A);
            ++g;
            if (g >= iters) break;
            A = issue(g + 1);
            compute(g, B);
            ++g;
        }

        bool valid = lane < deg_h;
        int typc = rc.x >> 20;
        int eidc = rc.y;
        // softmax 1 over d2
        float m1 = valid ? d2c : NEG_INF;
#pragma unroll
        for (int m = 32; m; m >>= 1) m1 = fmaxf(m1, __shfl_xor(m1, m));
        float e1 = valid ? expf(d2c - m1) : 0.f;
        float s1 = e1;
#pragma unroll
        for (int m = 32; m; m >>= 1) s1 += __shfl_xor(s1, m);
        float rs = e1 / s1;
        // trip score + softmax 2
        float stv = d1c + rs * rs * rel_norm[typc];
        float m2 = valid ? stv : NEG_INF;
#pragma unroll
        for (int m = 32; m; m >>= 1) m2 = fmaxf(m2, __shfl_xor(m2, m));
        float e2 = valid ? expf(stv - m2) : 0.f;
        float s2 = e2;
#pragma unroll
        for (int m = 32; m; m >>= 1) s2 += __shfl_xor(s2, m);
        if (valid) out[eidc] = e2 / s2;
    } else {
        // slow path (deg > 64): multi-sweep via sc scratch, 16 lanes/edge
        int grp = lane >> 4;
        int sub = lane & 15;
        const float4* hp = (const float4*)(ent + (size_t)wid * CHANNEL);
        float4 h0 = hp[sub], h1 = hp[sub + 16];

        float pm1 = NEG_INF;
        for (int k0 = 0; k0 < deg_h; k0 += 4) {
            int idx = k0 + grp;
            bool act = idx < deg_h;
            int j = s0 + (act ? idx : 0);
            int2 rc = recs[j];
            float d1 = 0.f, d2 = 0.f;
            if (act) {
                int tail = rc.x & 0xFFFFF;
                int typ = rc.x >> 20;
                const float4* tp = (const float4*)(ent + (size_t)tail * CHANNEL);
                const float4* rp = (const float4*)(P2 + typ * CHANNEL);
                float4 t0 = tp[sub], t1 = tp[sub + 16];
                float4 r0 = rp[sub], r1 = rp[sub + 16];
                d1 = dot4(h0, t0) + dot4(h1, t1);
                d2 = dot4(h0, r0) + dot4(h1, r1);
            }
#pragma unroll
            for (int m = 1; m <= 8; m <<= 1) {
                d1 += __shfl_xor(d1, m);
                d2 += __shfl_xor(d2, m);
            }
            if (act) {
                if (sub == 0) sc[j] = make_float2(d1, d2);
                pm1 = fmaxf(pm1, d2);
            }
        }
        pm1 = fmaxf(pm1, __shfl_xor(pm1, 16));
        pm1 = fmaxf(pm1, __shfl_xor(pm1, 32));
        float m1 = pm1;

        float s1 = 0.f;
        for (int k = lane; k < deg_h; k += 64) s1 += expf(sc[s0 + k].y - m1);
#pragma unroll
        for (int m = 32; m; m >>= 1) s1 += __shfl_xor(s1, m);

        float pm2 = NEG_INF;
        for (int k = lane; k < deg_h; k += 64) {
            float2 v = sc[s0 + k];
            int typ = recs[s0 + k].x >> 20;
            float e1 = expf(v.y - m1);
            float rsv = e1 / s1;
            float stv = v.x + rsv * rsv * rel_norm[typ];
            sc[s0 + k].x = stv;
            pm2 = fmaxf(pm2, stv);
        }
#pragma unroll
        for (int m = 32; m; m >>= 1) pm2 = fmaxf(pm2, __shfl_xor(pm2, m));
        float m2 = pm2;

        float s2 = 0.f;
        for (int k = lane; k < deg_h; k += 64) {
            float e2 = expf(sc[s0 + k].x - m2);
            sc[s0 + k].y = e2;
            s2 += e2;
        }
#pragma unroll
        for (int m = 32; m; m >>= 1) s2 += __shfl_xor(s2, m);
        float inv = 1.f / s2;

        for (int k = lane; k < deg_h; k += 64)
            out[recs[s0 + k].y] = sc[s0 + k].y * inv;
    }
}

extern "C" void kernel_launch(void* const* d_in, const int* in_sizes, int n_in,
                              void* d_out, int out_size, void* d_ws, size_t ws_size,
                              hipStream_t stream) {
    const float* ent   = (const float*)d_in[0];
    const float* relw  = (const float*)d_in[2];
    const float* W     = (const float*)d_in[3];
    const int*   eidx  = (const int*)d_in[4];
    const int*   etype = (const int*)d_in[5];
    float* out = (float*)d_out;

    const int E = in_sizes[5];
    const int N = in_sizes[0] / CHANNEL;
    const int R = in_sizes[2] / CHANNEL;

    char* base = (char*)d_ws;
    auto alloc = [&](size_t bytes) {
        char* p = base;
        base += (bytes + 15) & ~(size_t)15;
        return p;
    };
    int*    deg      = (int*)alloc((size_t)N * 4);
    int*    raw      = (int*)alloc((size_t)N * 4);
    int*    partial  = (int*)alloc(1024 * 4);
    int2*   recs     = (int2*)alloc((size_t)E * 8);
    float*  P2       = (float*)alloc((size_t)R * CHANNEL * 4);
    float*  rel_norm = (float*)alloc((size_t)R * 4);
    float2* sc       = (float2*)alloc((size_t)E * 8);
    // rank aliases sc: rank is dead before sc's first use (slow path in main)
    unsigned short* rank = (unsigned short*)sc;

    hipMemsetAsync(deg, 0, (size_t)N * 4, stream);

    int ceblk = (E + 255) / 256;
    prep_count_kernel<<<R + ceblk, 256, 0, stream>>>(relw, W, eidx, P2, rel_norm,
                                                     deg, rank, E, R);

    int nblk = (N + 255) / 256;  // 157 for N=40000; must be <= 1024
    scan1_kernel<<<nblk, 256, 0, stream>>>(deg, raw, partial, N);
    scan2_kernel<<<1, 1024, 0, stream>>>(partial, nblk);

    place_kernel<<<ceblk, 256, 0, stream>>>(eidx, etype, raw, partial, rank, recs, E);

    int bm = (N + 3) / 4;  // 4 waves per block, one wave per head
    main_kernel<<<bm, 256, 0, stream>>>(ent, P2, rel_norm, raw, partial, recs, sc, out, N, E);
}